// Round 13
// baseline (284.613 us; speedup 1.0000x reference)
//
#include <hip/hip_runtime.h>
#include <hip/hip_fp16.h>

#define H_ 1024
#define W_ 1024
#define RAD 30
#define EPSF 1.3f
#define SH 16            // output rows per block (even; 2-row batches)
#define NSEG (H_ / SH)   // 64 y-segments
#define NT 512           // 8 waves; 2 px/thread over the full 1024-px row
#define NXCD 8
#define CHMAX 8          // planes per chunk: keep chunk working set << L3

// ---- DPP wave64 inclusive scan: 6 VALU adds, no LDS traffic ----
#define DPP_ADD(v, ctrl, rmask, bc)                                            \
    ((v) + __int_as_float(__builtin_amdgcn_update_dpp(                         \
               0, __float_as_int(v), (ctrl), (rmask), 0xf, (bc))))

__device__ __forceinline__ float wscan_dpp(float v) {
    v = DPP_ADD(v, 0x111, 0xf, true);   // row_shr:1
    v = DPP_ADD(v, 0x112, 0xf, true);   // row_shr:2
    v = DPP_ADD(v, 0x114, 0xf, true);   // row_shr:4
    v = DPP_ADD(v, 0x118, 0xf, true);   // row_shr:8
    v = DPP_ADD(v, 0x142, 0xa, false);  // row_bcast:15 -> rows 1,3
    v = DPP_ADD(v, 0x143, 0xc, false);  // row_bcast:31 -> rows 2,3
    return v;
}

// ---- non-temporal 8B helpers (keep L3 for reused data) ----
__device__ __forceinline__ void nt_store_u64(void* p, unsigned long long v) {
    __builtin_nontemporal_store(v, (unsigned long long*)p);
}
__device__ __forceinline__ unsigned long long nt_load_u64(const void* p) {
    return __builtin_nontemporal_load((const unsigned long long*)p);
}

// ---------------------------------------------------------------------------
// gf_ab: block = (plane, 16-row segment), 512 threads, full-width row.
// Prefix arrays pos-major: P2[pos*5 + k], k=0..3 data float2 slots
// (k=0: row0{R,I}, k=1: row0{RI,RR}, k=2: row1{R,I}, k=3: row1{RI,RR}),
// k=4 pad. All LDS traffic b64/b128. Chunked launch keeps I/R L3-resident
// so halo/warm-up re-reads never hit HBM.
// ---------------------------------------------------------------------------
__global__ __launch_bounds__(NT, 6)
void gf_ab(const float* __restrict__ I, const float* __restrict__ R,
           long long in_off, int nb, __half2* __restrict__ AB)
{
    __shared__ float2 P2[(W_ + 1) * 5];   // 41 KB
    __shared__ float4 WT[8][2];           // per-wave scan totals (8 channels)

    // bijective XCD swizzle (nb % 8 == 0): consecutive segs -> same XCD
    const int q = nb / NXCD;
    const int bid = (int)blockIdx.x;
    const int sbid = (bid % NXCD) * q + bid / NXCD;
    const int seg = sbid % NSEG;
    const int pl  = sbid / NSEG;

    const int tid = threadIdx.x;
    const int lane = tid & 63;
    const int wid = __builtin_amdgcn_readfirstlane(tid) >> 6;  // wave-uniform
    const int x0 = tid * 2;
    const int y0 = seg * SH;
    const long long pb = (long long)pl * (long long)(H_ * W_);
    const long long ib = in_off + pb;

    float icx[2];
#pragma unroll
    for (int j = 0; j < 2; ++j) {
        const int x = x0 + j;
        icx[j] = 1.0f / (float)(min(x + RAD, W_ - 1) - max(x - RAD, 0) + 1);
    }

    if (tid == 0) {
#pragma unroll
        for (int k = 0; k < 4; ++k) P2[k] = make_float2(0.0f, 0.0f);  // pos 0
    }

    float s[4][2];
#pragma unroll
    for (int f = 0; f < 4; ++f) { s[f][0] = 0.0f; s[f][1] = 0.0f; }

    // warm-up rows [y0-RAD, y0+RAD] clipped
    {
        const int wlo = max(0, y0 - RAD), whi = min(H_ - 1, y0 + RAD);
#pragma unroll 4
        for (int yy = wlo; yy <= whi; ++yy) {
            const float2 r2 = *(const float2*)(R + ib + (long long)yy * W_ + x0);
            const float2 i2 = *(const float2*)(I + ib + (long long)yy * W_ + x0);
            s[0][0] += r2.x; s[0][1] += r2.y;
            s[1][0] += i2.x; s[1][1] += i2.y;
            s[2][0] += r2.x * i2.x; s[2][1] += r2.y * i2.y;
            s[3][0] += r2.x * r2.x; s[3][1] += r2.y * r2.y;
        }
    }

    for (int y = y0; y < y0 + SH; y += 2) {
        float ps[8][2], tot[8], wsc[8];

        // ---- snapshot row y, slide; snapshot row y+1, slide ----
#pragma unroll
        for (int r = 0; r < 2; ++r) {
            const int yr = y + r;
#pragma unroll
            for (int f = 0; f < 4; ++f) {
                ps[r * 4 + f][0] = s[f][0];
                ps[r * 4 + f][1] = s[f][0] + s[f][1];
            }
            const int ya = yr + RAD + 1, yb = yr - RAD;
            if (ya < H_) {
                const float2 r2 = *(const float2*)(R + ib + (long long)ya * W_ + x0);
                const float2 i2 = *(const float2*)(I + ib + (long long)ya * W_ + x0);
                s[0][0] += r2.x; s[0][1] += r2.y;
                s[1][0] += i2.x; s[1][1] += i2.y;
                s[2][0] += r2.x * i2.x; s[2][1] += r2.y * i2.y;
                s[3][0] += r2.x * r2.x; s[3][1] += r2.y * r2.y;
            }
            if (yb >= 0) {
                const float2 r2 = *(const float2*)(R + ib + (long long)yb * W_ + x0);
                const float2 i2 = *(const float2*)(I + ib + (long long)yb * W_ + x0);
                s[0][0] -= r2.x; s[0][1] -= r2.y;
                s[1][0] -= i2.x; s[1][1] -= i2.y;
                s[2][0] -= r2.x * i2.x; s[2][1] -= r2.y * i2.y;
                s[3][0] -= r2.x * r2.x; s[3][1] -= r2.y * r2.y;
            }
        }

        // ---- 8 independent DPP wave scans ----
#pragma unroll
        for (int ch = 0; ch < 8; ++ch) {
            tot[ch] = ps[ch][1];
            wsc[ch] = wscan_dpp(tot[ch]);
        }
        if (lane == 63) {
            WT[wid][0] = make_float4(wsc[0], wsc[1], wsc[2], wsc[3]);
            WT[wid][1] = make_float4(wsc[4], wsc[5], wsc[6], wsc[7]);
        }
        __syncthreads();   // b1: WT visible (also fences prev batch's P2 reads)

        // wave-uniform combine loop (<=7 iters, 2 x b128 each)
        float woA[4] = {0, 0, 0, 0}, woB[4] = {0, 0, 0, 0};
        for (int w = 0; w < wid; ++w) {
            const float4 a = WT[w][0], b = WT[w][1];
            woA[0] += a.x; woA[1] += a.y; woA[2] += a.z; woA[3] += a.w;
            woB[0] += b.x; woB[1] += b.y; woB[2] += b.z; woB[3] += b.w;
        }

        float pv1[8], pv2[8];
#pragma unroll
        for (int qd = 0; qd < 4; ++qd) {
            const float exA = woA[qd] + wsc[qd] - tot[qd];
            pv1[qd] = exA + ps[qd][0];
            pv2[qd] = exA + ps[qd][1];
            const float exB = woB[qd] + wsc[4 + qd] - tot[4 + qd];
            pv1[4 + qd] = exB + ps[4 + qd][0];
            pv2[4 + qd] = exB + ps[4 + qd][1];
        }
        {
            const int i1 = (x0 + 1) * 5, i2 = (x0 + 2) * 5;
            P2[i1 + 0] = make_float2(pv1[0], pv1[1]);
            P2[i1 + 1] = make_float2(pv1[2], pv1[3]);
            P2[i1 + 2] = make_float2(pv1[4], pv1[5]);
            P2[i1 + 3] = make_float2(pv1[6], pv1[7]);
            P2[i2 + 0] = make_float2(pv2[0], pv2[1]);
            P2[i2 + 1] = make_float2(pv2[2], pv2[3]);
            P2[i2 + 2] = make_float2(pv2[4], pv2[5]);
            P2[i2 + 3] = make_float2(pv2[6], pv2[7]);
        }
        __syncthreads();   // b2: P2 visible

#pragma unroll
        for (int r = 0; r < 2; ++r) {
            const int yr = y + r;
            const float icy = 1.0f / (float)(min(yr + RAD, H_ - 1) - max(yr - RAD, 0) + 1);
            __half2 hv[2];
#pragma unroll
            for (int j = 0; j < 2; ++j) {
                const int x = x0 + j;
                const int hi = min(x + RAD + 1, W_) * 5;
                const int lo = max(x - RAD, 0) * 5;
                const float2 ha = P2[hi + 2 * r + 0];
                const float2 hb = P2[hi + 2 * r + 1];
                const float2 la = P2[lo + 2 * r + 0];
                const float2 lb = P2[lo + 2 * r + 1];
                const float SR = ha.x - la.x;
                const float SI = ha.y - la.y;
                const float SP = hb.x - lb.x;
                const float SQ = hb.y - lb.y;
                const float invN = icx[j] * icy;
                const float mR = SR * invN, mI = SI * invN;
                const float a = (SP * invN - mR * mI) / (SQ * invN - mR * mR + EPSF);
                const float b = mI - a * mR;
                hv[j] = __floats2half2_rn(a, b);
            }
            unsigned long long u =
                (unsigned long long)(*(const unsigned*)&hv[0]) |
                ((unsigned long long)(*(const unsigned*)&hv[1]) << 32);
            nt_store_u64(AB + pb + (long long)yr * W_ + x0, u);
        }
        // no b3: next batch's b1 orders P2/WT reads vs writes.
    }
}

// ---------------------------------------------------------------------------
// gf_cd: same structure over packed half2 {a,b}; out = mean_a * R + mean_b.
// P2[pos*3 + k]: k=0: row0{a,b}, k=1: row1{a,b}, k=2 pad.
// ---------------------------------------------------------------------------
__global__ __launch_bounds__(NT, 6)
void gf_cd(const __half2* __restrict__ AB, const float* __restrict__ Rimg,
           long long in_off, int nb, float* __restrict__ out)
{
    __shared__ float2 P2[(W_ + 1) * 3];   // 24.6 KB
    __shared__ float4 WT[8][1];

    const int q = nb / NXCD;
    const int bid = (int)blockIdx.x;
    const int sbid = (bid % NXCD) * q + bid / NXCD;
    const int seg = sbid % NSEG;
    const int pl  = sbid / NSEG;

    const int tid = threadIdx.x;
    const int lane = tid & 63;
    const int wid = __builtin_amdgcn_readfirstlane(tid) >> 6;
    const int x0 = tid * 2;
    const int y0 = seg * SH;
    const long long pb = (long long)pl * (long long)(H_ * W_);
    const long long ib = in_off + pb;

    float icx[2];
#pragma unroll
    for (int j = 0; j < 2; ++j) {
        const int x = x0 + j;
        icx[j] = 1.0f / (float)(min(x + RAD, W_ - 1) - max(x - RAD, 0) + 1);
    }

    if (tid == 0) {
        P2[0] = make_float2(0.0f, 0.0f);
        P2[1] = make_float2(0.0f, 0.0f);
    }

    float s[2][2];
    s[0][0] = s[0][1] = s[1][0] = s[1][1] = 0.0f;

    {
        const int wlo = max(0, y0 - RAD), whi = min(H_ - 1, y0 + RAD);
#pragma unroll 4
        for (int yy = wlo; yy <= whi; ++yy) {
            const uint2 u = *(const uint2*)(AB + pb + (long long)yy * W_ + x0);
            const float2 a0 = __half22float2(*(const __half2*)&u.x);
            const float2 a1 = __half22float2(*(const __half2*)&u.y);
            s[0][0] += a0.x; s[1][0] += a0.y;
            s[0][1] += a1.x; s[1][1] += a1.y;
        }
    }

    for (int y = y0; y < y0 + SH; y += 2) {
        float ps[4][2], tot[4], wsc[4];

#pragma unroll
        for (int r = 0; r < 2; ++r) {
            const int yr = y + r;
#pragma unroll
            for (int f = 0; f < 2; ++f) {
                ps[r * 2 + f][0] = s[f][0];
                ps[r * 2 + f][1] = s[f][0] + s[f][1];
            }
            const int ya = yr + RAD + 1, yb = yr - RAD;
            if (ya < H_) {
                const uint2 u = *(const uint2*)(AB + pb + (long long)ya * W_ + x0);
                const float2 a0 = __half22float2(*(const __half2*)&u.x);
                const float2 a1 = __half22float2(*(const __half2*)&u.y);
                s[0][0] += a0.x; s[1][0] += a0.y;
                s[0][1] += a1.x; s[1][1] += a1.y;
            }
            if (yb >= 0) {
                const uint2 u = *(const uint2*)(AB + pb + (long long)yb * W_ + x0);
                const float2 a0 = __half22float2(*(const __half2*)&u.x);
                const float2 a1 = __half22float2(*(const __half2*)&u.y);
                s[0][0] -= a0.x; s[1][0] -= a0.y;
                s[0][1] -= a1.x; s[1][1] -= a1.y;
            }
        }

#pragma unroll
        for (int ch = 0; ch < 4; ++ch) {
            tot[ch] = ps[ch][1];
            wsc[ch] = wscan_dpp(tot[ch]);
        }
        if (lane == 63)
            WT[wid][0] = make_float4(wsc[0], wsc[1], wsc[2], wsc[3]);
        __syncthreads();   // b1

        float wo[4] = {0, 0, 0, 0};
        for (int w = 0; w < wid; ++w) {
            const float4 a = WT[w][0];
            wo[0] += a.x; wo[1] += a.y; wo[2] += a.z; wo[3] += a.w;
        }

        float pv1[4], pv2[4];
#pragma unroll
        for (int ch = 0; ch < 4; ++ch) {
            const float ex = wo[ch] + wsc[ch] - tot[ch];
            pv1[ch] = ex + ps[ch][0];
            pv2[ch] = ex + ps[ch][1];
        }
        {
            const int i1 = (x0 + 1) * 3, i2 = (x0 + 2) * 3;
            P2[i1 + 0] = make_float2(pv1[0], pv1[1]);
            P2[i1 + 1] = make_float2(pv1[2], pv1[3]);
            P2[i2 + 0] = make_float2(pv2[0], pv2[1]);
            P2[i2 + 1] = make_float2(pv2[2], pv2[3]);
        }
        __syncthreads();   // b2

#pragma unroll
        for (int r = 0; r < 2; ++r) {
            const int yr = y + r;
            const float icy = 1.0f / (float)(min(yr + RAD, H_ - 1) - max(yr - RAD, 0) + 1);
            const long long og = ib + (long long)yr * W_ + x0;
            const unsigned long long ru = nt_load_u64(Rimg + og);
            float rv[2];
            *(unsigned*)&rv[0] = (unsigned)(ru & 0xffffffffu);
            *(unsigned*)&rv[1] = (unsigned)(ru >> 32);
            float ov[2];
#pragma unroll
            for (int j = 0; j < 2; ++j) {
                const int x = x0 + j;
                const int hi = min(x + RAD + 1, W_) * 3;
                const int lo = max(x - RAD, 0) * 3;
                const float2 h2 = P2[hi + r];
                const float2 l2 = P2[lo + r];
                const float SA = h2.x - l2.x;
                const float SB = h2.y - l2.y;
                const float invN = icx[j] * icy;
                ov[j] = (SA * invN) * rv[j] + SB * invN;
            }
            unsigned long long uo =
                (unsigned long long)(*(const unsigned*)&ov[0]) |
                ((unsigned long long)(*(const unsigned*)&ov[1]) << 32);
            nt_store_u64(out + og, uo);
        }
        // no b3 (see gf_ab)
    }
}

// ---------------------------------------------------------------------------
extern "C" void kernel_launch(void* const* d_in, const int* in_sizes, int n_in,
                              void* d_out, int out_size, void* d_ws, size_t ws_size,
                              hipStream_t stream)
{
    const float* I = (const float*)d_in[0];   // image to filter
    const float* R = (const float*)d_in[1];   // guidance image
    float* out = (float*)d_out;

    const long long plane = (long long)H_ * W_;
    const int P_ = (int)(in_sizes[0] / plane);              // 24 planes
    const size_t ab_pb = (size_t)plane * sizeof(__half2);   // 4 MB/plane

    int CH = (int)(ws_size / ab_pb);
    if (CH > CHMAX) CH = CHMAX;   // L3 blocking: chunk working set ~96 MB
    if (CH > P_) CH = P_;
    if (CH < 1) CH = 1;

    __half2* AB = (__half2*)d_ws;

    for (int p0 = 0; p0 < P_; p0 += CH) {
        const int pc = (P_ - p0 < CH) ? (P_ - p0) : CH;
        const long long in_off = (long long)p0 * plane;
        const int nb = NSEG * pc;   // 64*pc => % 8 == 0

        hipLaunchKernelGGL(gf_ab, dim3(nb), dim3(NT), 0, stream,
                           I, R, in_off, nb, AB);
        hipLaunchKernelGGL(gf_cd, dim3(nb), dim3(NT), 0, stream,
                           AB, R, in_off, nb, out);
    }
}

// Round 14
// 218.869 us; speedup vs baseline: 1.3004x; 1.3004x over previous
//
#include <hip/hip_runtime.h>
#include <hip/hip_fp16.h>

#define H_ 1024
#define W_ 1024
#define RAD 30
#define EPSF 1.3f
#define SH 32            // output rows per block (even; 2-row batches)
#define NSEG (H_ / SH)   // 32 y-segments
#define NT 512           // 8 waves; 2 px/thread over the full 1024-px row
#define NXCD 8

// ---- DPP wave64 inclusive scan: 6 VALU adds, no LDS traffic ----
#define DPP_ADD(v, ctrl, rmask, bc)                                            \
    ((v) + __int_as_float(__builtin_amdgcn_update_dpp(                         \
               0, __float_as_int(v), (ctrl), (rmask), 0xf, (bc))))

__device__ __forceinline__ float wscan_dpp(float v) {
    v = DPP_ADD(v, 0x111, 0xf, true);   // row_shr:1
    v = DPP_ADD(v, 0x112, 0xf, true);   // row_shr:2
    v = DPP_ADD(v, 0x114, 0xf, true);   // row_shr:4
    v = DPP_ADD(v, 0x118, 0xf, true);   // row_shr:8
    v = DPP_ADD(v, 0x142, 0xa, false);  // row_bcast:15 -> rows 1,3
    v = DPP_ADD(v, 0x143, 0xc, false);  // row_bcast:31 -> rows 2,3
    return v;
}

// ---- non-temporal 8B helpers (keep L3 for reused data) ----
__device__ __forceinline__ void nt_store_u64(void* p, unsigned long long v) {
    __builtin_nontemporal_store(v, (unsigned long long*)p);
}
__device__ __forceinline__ unsigned long long nt_load_u64(const void* p) {
    return __builtin_nontemporal_load((const unsigned long long*)p);
}

// ---------------------------------------------------------------------------
// gf_ab: block = (plane, 32-row segment), 512 threads, full-width row.
// Pos-major prefix LDS: P2[pos*5 + k] (k=0..3 data float2, k=4 pad).
// Slide loads for batch k+1 are issued in batch k and kept in REGISTERS:
// __launch_bounds__(NT,4) raises the VGPR budget so the compiler does not
// spill them to scratch (R8/R11 failure mode: bounds(NT,6) -> spills ->
// WRITE/FETCH inflation). 2 blocks/CU also shrinks the concurrent halo
// working set vs 3 (R12 lesson: wider set -> HBM blowup).
// ---------------------------------------------------------------------------
__global__ __launch_bounds__(NT, 4)
void gf_ab(const float* __restrict__ I, const float* __restrict__ R,
           long long in_off, int nb, __half2* __restrict__ AB)
{
    __shared__ float2 P2[(W_ + 1) * 5];   // 41 KB
    __shared__ float4 WT[8][2];           // per-wave scan totals (8 channels)

    // bijective XCD swizzle (nb % 8 == 0): consecutive segs -> same XCD
    const int q = nb / NXCD;
    const int bid = (int)blockIdx.x;
    const int sbid = (bid % NXCD) * q + bid / NXCD;
    const int seg = sbid % NSEG;
    const int pl  = sbid / NSEG;

    const int tid = threadIdx.x;
    const int lane = tid & 63;
    const int wid = __builtin_amdgcn_readfirstlane(tid) >> 6;  // wave-uniform
    const int x0 = tid * 2;
    const int y0 = seg * SH;
    const long long pb = (long long)pl * (long long)(H_ * W_);
    const long long ib = in_off + pb;

    float icx[2];
#pragma unroll
    for (int j = 0; j < 2; ++j) {
        const int x = x0 + j;
        icx[j] = 1.0f / (float)(min(x + RAD, W_ - 1) - max(x - RAD, 0) + 1);
    }

    if (tid == 0) {
#pragma unroll
        for (int k = 0; k < 4; ++k) P2[k] = make_float2(0.0f, 0.0f);  // pos 0
    }

    float s[4][2];
#pragma unroll
    for (int f = 0; f < 4; ++f) { s[f][0] = 0.0f; s[f][1] = 0.0f; }

    // warm-up rows [y0-RAD, y0+RAD] clipped
    {
        const int wlo = max(0, y0 - RAD), whi = min(H_ - 1, y0 + RAD);
#pragma unroll 4
        for (int yy = wlo; yy <= whi; ++yy) {
            const float2 r2 = *(const float2*)(R + ib + (long long)yy * W_ + x0);
            const float2 i2 = *(const float2*)(I + ib + (long long)yy * W_ + x0);
            s[0][0] += r2.x; s[0][1] += r2.y;
            s[1][0] += i2.x; s[1][1] += i2.y;
            s[2][0] += r2.x * i2.x; s[2][1] += r2.y * i2.y;
            s[3][0] += r2.x * r2.x; s[3][1] += r2.y * r2.y;
        }
    }

    const float2 z2 = make_float2(0.0f, 0.0f);
    // prefetch registers for next batch's 4 slide rows x {R,I}
    float2 pA0r, pA0i, pA1r, pA1i, pS0r, pS0i, pS1r, pS1i;
#define PF_AB(yy)                                                              \
    {                                                                          \
        const int A0 = (yy) + RAD + 1, A1 = (yy) + RAD + 2;                    \
        const int B0 = (yy) - RAD,     B1 = (yy) - RAD + 1;                    \
        pA0r = z2; pA0i = z2; pA1r = z2; pA1i = z2;                            \
        pS0r = z2; pS0i = z2; pS1r = z2; pS1i = z2;                            \
        if (A0 < H_) {                                                         \
            pA0r = *(const float2*)(R + ib + (long long)A0 * W_ + x0);         \
            pA0i = *(const float2*)(I + ib + (long long)A0 * W_ + x0);         \
        }                                                                      \
        if (A1 < H_) {                                                         \
            pA1r = *(const float2*)(R + ib + (long long)A1 * W_ + x0);         \
            pA1i = *(const float2*)(I + ib + (long long)A1 * W_ + x0);         \
        }                                                                      \
        if (B0 >= 0) {                                                         \
            pS0r = *(const float2*)(R + ib + (long long)B0 * W_ + x0);         \
            pS0i = *(const float2*)(I + ib + (long long)B0 * W_ + x0);         \
        }                                                                      \
        if (B1 >= 0) {                                                         \
            pS1r = *(const float2*)(R + ib + (long long)B1 * W_ + x0);         \
            pS1i = *(const float2*)(I + ib + (long long)B1 * W_ + x0);         \
        }                                                                      \
    }

    PF_AB(y0);   // prologue prefetch for first batch

    for (int y = y0; y < y0 + SH; y += 2) {
        float ps[8][2], tot[8], wsc[8];

        // ---- consume prefetched slides; snapshot both rows ----
#pragma unroll
        for (int f = 0; f < 4; ++f) {
            ps[0 * 4 + f][0] = s[f][0];
            ps[0 * 4 + f][1] = s[f][0] + s[f][1];
        }
        s[0][0] += pA0r.x - pS0r.x;               s[0][1] += pA0r.y - pS0r.y;
        s[1][0] += pA0i.x - pS0i.x;               s[1][1] += pA0i.y - pS0i.y;
        s[2][0] += pA0r.x * pA0i.x - pS0r.x * pS0i.x;
        s[2][1] += pA0r.y * pA0i.y - pS0r.y * pS0i.y;
        s[3][0] += pA0r.x * pA0r.x - pS0r.x * pS0r.x;
        s[3][1] += pA0r.y * pA0r.y - pS0r.y * pS0r.y;
#pragma unroll
        for (int f = 0; f < 4; ++f) {
            ps[1 * 4 + f][0] = s[f][0];
            ps[1 * 4 + f][1] = s[f][0] + s[f][1];
        }
        s[0][0] += pA1r.x - pS1r.x;               s[0][1] += pA1r.y - pS1r.y;
        s[1][0] += pA1i.x - pS1i.x;               s[1][1] += pA1i.y - pS1i.y;
        s[2][0] += pA1r.x * pA1i.x - pS1r.x * pS1i.x;
        s[2][1] += pA1r.y * pA1i.y - pS1r.y * pS1i.y;
        s[3][0] += pA1r.x * pA1r.x - pS1r.x * pS1r.x;
        s[3][1] += pA1r.y * pA1r.y - pS1r.y * pS1r.y;

        // ---- issue NEXT batch's loads; latency hides under scan+LDS+solve ----
        if (y + 2 < y0 + SH) PF_AB(y + 2);

        // ---- 8 independent DPP wave scans ----
#pragma unroll
        for (int ch = 0; ch < 8; ++ch) {
            tot[ch] = ps[ch][1];
            wsc[ch] = wscan_dpp(tot[ch]);
        }
        if (lane == 63) {
            WT[wid][0] = make_float4(wsc[0], wsc[1], wsc[2], wsc[3]);
            WT[wid][1] = make_float4(wsc[4], wsc[5], wsc[6], wsc[7]);
        }
        __syncthreads();   // b1: WT visible (also fences prev batch's P2 reads)

        // wave-uniform combine loop (<=7 iters, 2 x b128 each)
        float woA[4] = {0, 0, 0, 0}, woB[4] = {0, 0, 0, 0};
        for (int w = 0; w < wid; ++w) {
            const float4 a = WT[w][0], b = WT[w][1];
            woA[0] += a.x; woA[1] += a.y; woA[2] += a.z; woA[3] += a.w;
            woB[0] += b.x; woB[1] += b.y; woB[2] += b.z; woB[3] += b.w;
        }

        float pv1[8], pv2[8];
#pragma unroll
        for (int qd = 0; qd < 4; ++qd) {
            const float exA = woA[qd] + wsc[qd] - tot[qd];
            pv1[qd] = exA + ps[qd][0];
            pv2[qd] = exA + ps[qd][1];
            const float exB = woB[qd] + wsc[4 + qd] - tot[4 + qd];
            pv1[4 + qd] = exB + ps[4 + qd][0];
            pv2[4 + qd] = exB + ps[4 + qd][1];
        }
        {
            const int i1 = (x0 + 1) * 5, i2 = (x0 + 2) * 5;
            P2[i1 + 0] = make_float2(pv1[0], pv1[1]);
            P2[i1 + 1] = make_float2(pv1[2], pv1[3]);
            P2[i1 + 2] = make_float2(pv1[4], pv1[5]);
            P2[i1 + 3] = make_float2(pv1[6], pv1[7]);
            P2[i2 + 0] = make_float2(pv2[0], pv2[1]);
            P2[i2 + 1] = make_float2(pv2[2], pv2[3]);
            P2[i2 + 2] = make_float2(pv2[4], pv2[5]);
            P2[i2 + 3] = make_float2(pv2[6], pv2[7]);
        }
        __syncthreads();   // b2: P2 visible

#pragma unroll
        for (int r = 0; r < 2; ++r) {
            const int yr = y + r;
            const float icy = 1.0f / (float)(min(yr + RAD, H_ - 1) - max(yr - RAD, 0) + 1);
            __half2 hv[2];
#pragma unroll
            for (int j = 0; j < 2; ++j) {
                const int x = x0 + j;
                const int hi = min(x + RAD + 1, W_) * 5;
                const int lo = max(x - RAD, 0) * 5;
                const float2 ha = P2[hi + 2 * r + 0];
                const float2 hb = P2[hi + 2 * r + 1];
                const float2 la = P2[lo + 2 * r + 0];
                const float2 lb = P2[lo + 2 * r + 1];
                const float SR = ha.x - la.x;
                const float SI = ha.y - la.y;
                const float SP = hb.x - lb.x;
                const float SQ = hb.y - lb.y;
                const float invN = icx[j] * icy;
                const float mR = SR * invN, mI = SI * invN;
                const float a = (SP * invN - mR * mI) / (SQ * invN - mR * mR + EPSF);
                const float b = mI - a * mR;
                hv[j] = __floats2half2_rn(a, b);
            }
            unsigned long long u =
                (unsigned long long)(*(const unsigned*)&hv[0]) |
                ((unsigned long long)(*(const unsigned*)&hv[1]) << 32);
            nt_store_u64(AB + pb + (long long)yr * W_ + x0, u);
        }
        // no b3: next batch's b1 orders P2/WT reads vs writes.
    }
#undef PF_AB
}

// ---------------------------------------------------------------------------
// gf_cd: unchanged from R10 (best). Packed half2 {a,b} in, out = ma*R + mb.
// P2[pos*3 + k]: k=0: row0{a,b}, k=1: row1{a,b}, k=2 pad.
// ---------------------------------------------------------------------------
__global__ __launch_bounds__(NT, 6)
void gf_cd(const __half2* __restrict__ AB, const float* __restrict__ Rimg,
           long long in_off, int nb, float* __restrict__ out)
{
    __shared__ float2 P2[(W_ + 1) * 3];   // 24.6 KB
    __shared__ float4 WT[8][1];

    const int q = nb / NXCD;
    const int bid = (int)blockIdx.x;
    const int sbid = (bid % NXCD) * q + bid / NXCD;
    const int seg = sbid % NSEG;
    const int pl  = sbid / NSEG;

    const int tid = threadIdx.x;
    const int lane = tid & 63;
    const int wid = __builtin_amdgcn_readfirstlane(tid) >> 6;
    const int x0 = tid * 2;
    const int y0 = seg * SH;
    const long long pb = (long long)pl * (long long)(H_ * W_);
    const long long ib = in_off + pb;

    float icx[2];
#pragma unroll
    for (int j = 0; j < 2; ++j) {
        const int x = x0 + j;
        icx[j] = 1.0f / (float)(min(x + RAD, W_ - 1) - max(x - RAD, 0) + 1);
    }

    if (tid == 0) {
        P2[0] = make_float2(0.0f, 0.0f);
        P2[1] = make_float2(0.0f, 0.0f);
    }

    float s[2][2];
    s[0][0] = s[0][1] = s[1][0] = s[1][1] = 0.0f;

    {
        const int wlo = max(0, y0 - RAD), whi = min(H_ - 1, y0 + RAD);
#pragma unroll 4
        for (int yy = wlo; yy <= whi; ++yy) {
            const uint2 u = *(const uint2*)(AB + pb + (long long)yy * W_ + x0);
            const float2 a0 = __half22float2(*(const __half2*)&u.x);
            const float2 a1 = __half22float2(*(const __half2*)&u.y);
            s[0][0] += a0.x; s[1][0] += a0.y;
            s[0][1] += a1.x; s[1][1] += a1.y;
        }
    }

    for (int y = y0; y < y0 + SH; y += 2) {
        float ps[4][2], tot[4], wsc[4];

#pragma unroll
        for (int r = 0; r < 2; ++r) {
            const int yr = y + r;
#pragma unroll
            for (int f = 0; f < 2; ++f) {
                ps[r * 2 + f][0] = s[f][0];
                ps[r * 2 + f][1] = s[f][0] + s[f][1];
            }
            const int ya = yr + RAD + 1, yb = yr - RAD;
            if (ya < H_) {
                const uint2 u = *(const uint2*)(AB + pb + (long long)ya * W_ + x0);
                const float2 a0 = __half22float2(*(const __half2*)&u.x);
                const float2 a1 = __half22float2(*(const __half2*)&u.y);
                s[0][0] += a0.x; s[1][0] += a0.y;
                s[0][1] += a1.x; s[1][1] += a1.y;
            }
            if (yb >= 0) {
                const uint2 u = *(const uint2*)(AB + pb + (long long)yb * W_ + x0);
                const float2 a0 = __half22float2(*(const __half2*)&u.x);
                const float2 a1 = __half22float2(*(const __half2*)&u.y);
                s[0][0] -= a0.x; s[1][0] -= a0.y;
                s[0][1] -= a1.x; s[1][1] -= a1.y;
            }
        }

#pragma unroll
        for (int ch = 0; ch < 4; ++ch) {
            tot[ch] = ps[ch][1];
            wsc[ch] = wscan_dpp(tot[ch]);
        }
        if (lane == 63)
            WT[wid][0] = make_float4(wsc[0], wsc[1], wsc[2], wsc[3]);
        __syncthreads();   // b1

        float wo[4] = {0, 0, 0, 0};
        for (int w = 0; w < wid; ++w) {
            const float4 a = WT[w][0];
            wo[0] += a.x; wo[1] += a.y; wo[2] += a.z; wo[3] += a.w;
        }

        float pv1[4], pv2[4];
#pragma unroll
        for (int ch = 0; ch < 4; ++ch) {
            const float ex = wo[ch] + wsc[ch] - tot[ch];
            pv1[ch] = ex + ps[ch][0];
            pv2[ch] = ex + ps[ch][1];
        }
        {
            const int i1 = (x0 + 1) * 3, i2 = (x0 + 2) * 3;
            P2[i1 + 0] = make_float2(pv1[0], pv1[1]);
            P2[i1 + 1] = make_float2(pv1[2], pv1[3]);
            P2[i2 + 0] = make_float2(pv2[0], pv2[1]);
            P2[i2 + 1] = make_float2(pv2[2], pv2[3]);
        }
        __syncthreads();   // b2

#pragma unroll
        for (int r = 0; r < 2; ++r) {
            const int yr = y + r;
            const float icy = 1.0f / (float)(min(yr + RAD, H_ - 1) - max(yr - RAD, 0) + 1);
            const long long og = ib + (long long)yr * W_ + x0;
            const unsigned long long ru = nt_load_u64(Rimg + og);
            float rv[2];
            *(unsigned*)&rv[0] = (unsigned)(ru & 0xffffffffu);
            *(unsigned*)&rv[1] = (unsigned)(ru >> 32);
            float ov[2];
#pragma unroll
            for (int j = 0; j < 2; ++j) {
                const int x = x0 + j;
                const int hi = min(x + RAD + 1, W_) * 3;
                const int lo = max(x - RAD, 0) * 3;
                const float2 h2 = P2[hi + r];
                const float2 l2 = P2[lo + r];
                const float SA = h2.x - l2.x;
                const float SB = h2.y - l2.y;
                const float invN = icx[j] * icy;
                ov[j] = (SA * invN) * rv[j] + SB * invN;
            }
            unsigned long long uo =
                (unsigned long long)(*(const unsigned*)&ov[0]) |
                ((unsigned long long)(*(const unsigned*)&ov[1]) << 32);
            nt_store_u64(out + og, uo);
        }
        // no b3 (see gf_ab)
    }
}

// ---------------------------------------------------------------------------
extern "C" void kernel_launch(void* const* d_in, const int* in_sizes, int n_in,
                              void* d_out, int out_size, void* d_ws, size_t ws_size,
                              hipStream_t stream)
{
    const float* I = (const float*)d_in[0];   // image to filter
    const float* R = (const float*)d_in[1];   // guidance image
    float* out = (float*)d_out;

    const long long plane = (long long)H_ * W_;
    const int P_ = (int)(in_sizes[0] / plane);              // 24 planes
    const size_t ab_pb = (size_t)plane * sizeof(__half2);   // 4 MB/plane

    int CH = (int)(ws_size / ab_pb);
    if (CH > P_) CH = P_;
    if (CH < 1) CH = 1;

    __half2* AB = (__half2*)d_ws;

    for (int p0 = 0; p0 < P_; p0 += CH) {
        const int pc = (P_ - p0 < CH) ? (P_ - p0) : CH;
        const long long in_off = (long long)p0 * plane;
        const int nb = NSEG * pc;   // 32*pc

        hipLaunchKernelGGL(gf_ab, dim3(nb), dim3(NT), 0, stream,
                           I, R, in_off, nb, AB);
        hipLaunchKernelGGL(gf_cd, dim3(nb), dim3(NT), 0, stream,
                           AB, R, in_off, nb, out);
    }
}

// Round 15
// 216.271 us; speedup vs baseline: 1.3160x; 1.0120x over previous
//
#include <hip/hip_runtime.h>
#include <hip/hip_fp16.h>

#define H_ 1024
#define W_ 1024
#define RAD 30
#define EPSF 1.3f
#define SH 32            // output rows per block (even; 2-row batches)
#define NSEG (H_ / SH)   // 32 y-segments
#define NT 512           // 8 waves; 2 px/thread over the full 1024-px row
#define NXCD 8

// ---- DPP wave64 inclusive scan: 6 VALU adds, no LDS traffic ----
#define DPP_ADD(v, ctrl, rmask, bc)                                            \
    ((v) + __int_as_float(__builtin_amdgcn_update_dpp(                         \
               0, __float_as_int(v), (ctrl), (rmask), 0xf, (bc))))

__device__ __forceinline__ float wscan_dpp(float v) {
    v = DPP_ADD(v, 0x111, 0xf, true);   // row_shr:1
    v = DPP_ADD(v, 0x112, 0xf, true);   // row_shr:2
    v = DPP_ADD(v, 0x114, 0xf, true);   // row_shr:4
    v = DPP_ADD(v, 0x118, 0xf, true);   // row_shr:8
    v = DPP_ADD(v, 0x142, 0xa, false);  // row_bcast:15 -> rows 1,3
    v = DPP_ADD(v, 0x143, 0xc, false);  // row_bcast:31 -> rows 2,3
    return v;
}

// ---- non-temporal 8B helpers (keep L3 for reused data) ----
__device__ __forceinline__ void nt_store_u64(void* p, unsigned long long v) {
    __builtin_nontemporal_store(v, (unsigned long long*)p);
}
__device__ __forceinline__ unsigned long long nt_load_u64(const void* p) {
    return __builtin_nontemporal_load((const unsigned long long*)p);
}

// ---------------------------------------------------------------------------
// gf_ab: block = (plane, 32-row segment), 512 threads, full-width row.
// Pos-major prefix LDS: P2[pos*5 + k] (k=0..3 data float2, k=4 pad).
// Slide loads for batch k+1 issued in batch k, kept in registers
// (__launch_bounds__(NT,4) -> no spill; WRITE_SIZE clean at 98304 KB).
// AB store is a PLAIN store (not NT): AB must stay L3-resident so gf_cd's
// reads + halo re-reads hit L3 instead of HBM (R15 change; R9's NT store
// was never isolated and penalizes cd).
// ---------------------------------------------------------------------------
__global__ __launch_bounds__(NT, 4)
void gf_ab(const float* __restrict__ I, const float* __restrict__ R,
           long long in_off, int nb, __half2* __restrict__ AB)
{
    __shared__ float2 P2[(W_ + 1) * 5];   // 41 KB
    __shared__ float4 WT[8][2];           // per-wave scan totals (8 channels)

    // bijective XCD swizzle (nb % 8 == 0): consecutive segs -> same XCD
    const int q = nb / NXCD;
    const int bid = (int)blockIdx.x;
    const int sbid = (bid % NXCD) * q + bid / NXCD;
    const int seg = sbid % NSEG;
    const int pl  = sbid / NSEG;

    const int tid = threadIdx.x;
    const int lane = tid & 63;
    const int wid = __builtin_amdgcn_readfirstlane(tid) >> 6;  // wave-uniform
    const int x0 = tid * 2;
    const int y0 = seg * SH;
    const long long pb = (long long)pl * (long long)(H_ * W_);
    const long long ib = in_off + pb;

    float icx[2];
#pragma unroll
    for (int j = 0; j < 2; ++j) {
        const int x = x0 + j;
        icx[j] = 1.0f / (float)(min(x + RAD, W_ - 1) - max(x - RAD, 0) + 1);
    }

    if (tid == 0) {
#pragma unroll
        for (int k = 0; k < 4; ++k) P2[k] = make_float2(0.0f, 0.0f);  // pos 0
    }

    float s[4][2];
#pragma unroll
    for (int f = 0; f < 4; ++f) { s[f][0] = 0.0f; s[f][1] = 0.0f; }

    // warm-up rows [y0-RAD, y0+RAD] clipped
    {
        const int wlo = max(0, y0 - RAD), whi = min(H_ - 1, y0 + RAD);
#pragma unroll 4
        for (int yy = wlo; yy <= whi; ++yy) {
            const float2 r2 = *(const float2*)(R + ib + (long long)yy * W_ + x0);
            const float2 i2 = *(const float2*)(I + ib + (long long)yy * W_ + x0);
            s[0][0] += r2.x; s[0][1] += r2.y;
            s[1][0] += i2.x; s[1][1] += i2.y;
            s[2][0] += r2.x * i2.x; s[2][1] += r2.y * i2.y;
            s[3][0] += r2.x * r2.x; s[3][1] += r2.y * r2.y;
        }
    }

    const float2 z2 = make_float2(0.0f, 0.0f);
    // prefetch registers for next batch's 4 slide rows x {R,I}
    float2 pA0r, pA0i, pA1r, pA1i, pS0r, pS0i, pS1r, pS1i;
#define PF_AB(yy)                                                              \
    {                                                                          \
        const int A0 = (yy) + RAD + 1, A1 = (yy) + RAD + 2;                    \
        const int B0 = (yy) - RAD,     B1 = (yy) - RAD + 1;                    \
        pA0r = z2; pA0i = z2; pA1r = z2; pA1i = z2;                            \
        pS0r = z2; pS0i = z2; pS1r = z2; pS1i = z2;                            \
        if (A0 < H_) {                                                         \
            pA0r = *(const float2*)(R + ib + (long long)A0 * W_ + x0);         \
            pA0i = *(const float2*)(I + ib + (long long)A0 * W_ + x0);         \
        }                                                                      \
        if (A1 < H_) {                                                         \
            pA1r = *(const float2*)(R + ib + (long long)A1 * W_ + x0);         \
            pA1i = *(const float2*)(I + ib + (long long)A1 * W_ + x0);         \
        }                                                                      \
        if (B0 >= 0) {                                                         \
            pS0r = *(const float2*)(R + ib + (long long)B0 * W_ + x0);         \
            pS0i = *(const float2*)(I + ib + (long long)B0 * W_ + x0);         \
        }                                                                      \
        if (B1 >= 0) {                                                         \
            pS1r = *(const float2*)(R + ib + (long long)B1 * W_ + x0);         \
            pS1i = *(const float2*)(I + ib + (long long)B1 * W_ + x0);         \
        }                                                                      \
    }

    PF_AB(y0);   // prologue prefetch for first batch

    for (int y = y0; y < y0 + SH; y += 2) {
        float ps[8][2], tot[8], wsc[8];

        // ---- consume prefetched slides; snapshot both rows ----
#pragma unroll
        for (int f = 0; f < 4; ++f) {
            ps[0 * 4 + f][0] = s[f][0];
            ps[0 * 4 + f][1] = s[f][0] + s[f][1];
        }
        s[0][0] += pA0r.x - pS0r.x;               s[0][1] += pA0r.y - pS0r.y;
        s[1][0] += pA0i.x - pS0i.x;               s[1][1] += pA0i.y - pS0i.y;
        s[2][0] += pA0r.x * pA0i.x - pS0r.x * pS0i.x;
        s[2][1] += pA0r.y * pA0i.y - pS0r.y * pS0i.y;
        s[3][0] += pA0r.x * pA0r.x - pS0r.x * pS0r.x;
        s[3][1] += pA0r.y * pA0r.y - pS0r.y * pS0r.y;
#pragma unroll
        for (int f = 0; f < 4; ++f) {
            ps[1 * 4 + f][0] = s[f][0];
            ps[1 * 4 + f][1] = s[f][0] + s[f][1];
        }
        s[0][0] += pA1r.x - pS1r.x;               s[0][1] += pA1r.y - pS1r.y;
        s[1][0] += pA1i.x - pS1i.x;               s[1][1] += pA1i.y - pS1i.y;
        s[2][0] += pA1r.x * pA1i.x - pS1r.x * pS1i.x;
        s[2][1] += pA1r.y * pA1i.y - pS1r.y * pS1i.y;
        s[3][0] += pA1r.x * pA1r.x - pS1r.x * pS1r.x;
        s[3][1] += pA1r.y * pA1r.y - pS1r.y * pS1r.y;

        // ---- issue NEXT batch's loads; latency hides under scan+LDS+solve ----
        if (y + 2 < y0 + SH) PF_AB(y + 2);

        // ---- 8 independent DPP wave scans ----
#pragma unroll
        for (int ch = 0; ch < 8; ++ch) {
            tot[ch] = ps[ch][1];
            wsc[ch] = wscan_dpp(tot[ch]);
        }
        if (lane == 63) {
            WT[wid][0] = make_float4(wsc[0], wsc[1], wsc[2], wsc[3]);
            WT[wid][1] = make_float4(wsc[4], wsc[5], wsc[6], wsc[7]);
        }
        __syncthreads();   // b1: WT visible (also fences prev batch's P2 reads)

        // wave-uniform combine loop (<=7 iters, 2 x b128 each)
        float woA[4] = {0, 0, 0, 0}, woB[4] = {0, 0, 0, 0};
        for (int w = 0; w < wid; ++w) {
            const float4 a = WT[w][0], b = WT[w][1];
            woA[0] += a.x; woA[1] += a.y; woA[2] += a.z; woA[3] += a.w;
            woB[0] += b.x; woB[1] += b.y; woB[2] += b.z; woB[3] += b.w;
        }

        float pv1[8], pv2[8];
#pragma unroll
        for (int qd = 0; qd < 4; ++qd) {
            const float exA = woA[qd] + wsc[qd] - tot[qd];
            pv1[qd] = exA + ps[qd][0];
            pv2[qd] = exA + ps[qd][1];
            const float exB = woB[qd] + wsc[4 + qd] - tot[4 + qd];
            pv1[4 + qd] = exB + ps[4 + qd][0];
            pv2[4 + qd] = exB + ps[4 + qd][1];
        }
        {
            const int i1 = (x0 + 1) * 5, i2 = (x0 + 2) * 5;
            P2[i1 + 0] = make_float2(pv1[0], pv1[1]);
            P2[i1 + 1] = make_float2(pv1[2], pv1[3]);
            P2[i1 + 2] = make_float2(pv1[4], pv1[5]);
            P2[i1 + 3] = make_float2(pv1[6], pv1[7]);
            P2[i2 + 0] = make_float2(pv2[0], pv2[1]);
            P2[i2 + 1] = make_float2(pv2[2], pv2[3]);
            P2[i2 + 2] = make_float2(pv2[4], pv2[5]);
            P2[i2 + 3] = make_float2(pv2[6], pv2[7]);
        }
        __syncthreads();   // b2: P2 visible

#pragma unroll
        for (int r = 0; r < 2; ++r) {
            const int yr = y + r;
            const float icy = 1.0f / (float)(min(yr + RAD, H_ - 1) - max(yr - RAD, 0) + 1);
            __half2 hv[2];
#pragma unroll
            for (int j = 0; j < 2; ++j) {
                const int x = x0 + j;
                const int hi = min(x + RAD + 1, W_) * 5;
                const int lo = max(x - RAD, 0) * 5;
                const float2 ha = P2[hi + 2 * r + 0];
                const float2 hb = P2[hi + 2 * r + 1];
                const float2 la = P2[lo + 2 * r + 0];
                const float2 lb = P2[lo + 2 * r + 1];
                const float SR = ha.x - la.x;
                const float SI = ha.y - la.y;
                const float SP = hb.x - lb.x;
                const float SQ = hb.y - lb.y;
                const float invN = icx[j] * icy;
                const float mR = SR * invN, mI = SI * invN;
                const float a = (SP * invN - mR * mI) / (SQ * invN - mR * mR + EPSF);
                const float b = mI - a * mR;
                hv[j] = __floats2half2_rn(a, b);
            }
            // PLAIN store (R15 change): keep AB in L3 for gf_cd.
            uint2 u;
            u.x = *(const unsigned*)&hv[0];
            u.y = *(const unsigned*)&hv[1];
            *(uint2*)(AB + pb + (long long)yr * W_ + x0) = u;
        }
        // no b3: next batch's b1 orders P2/WT reads vs writes.
    }
#undef PF_AB
}

// ---------------------------------------------------------------------------
// gf_cd: unchanged. Packed half2 {a,b} in (now L3-hot), out = ma*R + mb.
// P2[pos*3 + k]: k=0: row0{a,b}, k=1: row1{a,b}, k=2 pad.
// ---------------------------------------------------------------------------
__global__ __launch_bounds__(NT, 6)
void gf_cd(const __half2* __restrict__ AB, const float* __restrict__ Rimg,
           long long in_off, int nb, float* __restrict__ out)
{
    __shared__ float2 P2[(W_ + 1) * 3];   // 24.6 KB
    __shared__ float4 WT[8][1];

    const int q = nb / NXCD;
    const int bid = (int)blockIdx.x;
    const int sbid = (bid % NXCD) * q + bid / NXCD;
    const int seg = sbid % NSEG;
    const int pl  = sbid / NSEG;

    const int tid = threadIdx.x;
    const int lane = tid & 63;
    const int wid = __builtin_amdgcn_readfirstlane(tid) >> 6;
    const int x0 = tid * 2;
    const int y0 = seg * SH;
    const long long pb = (long long)pl * (long long)(H_ * W_);
    const long long ib = in_off + pb;

    float icx[2];
#pragma unroll
    for (int j = 0; j < 2; ++j) {
        const int x = x0 + j;
        icx[j] = 1.0f / (float)(min(x + RAD, W_ - 1) - max(x - RAD, 0) + 1);
    }

    if (tid == 0) {
        P2[0] = make_float2(0.0f, 0.0f);
        P2[1] = make_float2(0.0f, 0.0f);
    }

    float s[2][2];
    s[0][0] = s[0][1] = s[1][0] = s[1][1] = 0.0f;

    {
        const int wlo = max(0, y0 - RAD), whi = min(H_ - 1, y0 + RAD);
#pragma unroll 4
        for (int yy = wlo; yy <= whi; ++yy) {
            const uint2 u = *(const uint2*)(AB + pb + (long long)yy * W_ + x0);
            const float2 a0 = __half22float2(*(const __half2*)&u.x);
            const float2 a1 = __half22float2(*(const __half2*)&u.y);
            s[0][0] += a0.x; s[1][0] += a0.y;
            s[0][1] += a1.x; s[1][1] += a1.y;
        }
    }

    for (int y = y0; y < y0 + SH; y += 2) {
        float ps[4][2], tot[4], wsc[4];

#pragma unroll
        for (int r = 0; r < 2; ++r) {
            const int yr = y + r;
#pragma unroll
            for (int f = 0; f < 2; ++f) {
                ps[r * 2 + f][0] = s[f][0];
                ps[r * 2 + f][1] = s[f][0] + s[f][1];
            }
            const int ya = yr + RAD + 1, yb = yr - RAD;
            if (ya < H_) {
                const uint2 u = *(const uint2*)(AB + pb + (long long)ya * W_ + x0);
                const float2 a0 = __half22float2(*(const __half2*)&u.x);
                const float2 a1 = __half22float2(*(const __half2*)&u.y);
                s[0][0] += a0.x; s[1][0] += a0.y;
                s[0][1] += a1.x; s[1][1] += a1.y;
            }
            if (yb >= 0) {
                const uint2 u = *(const uint2*)(AB + pb + (long long)yb * W_ + x0);
                const float2 a0 = __half22float2(*(const __half2*)&u.x);
                const float2 a1 = __half22float2(*(const __half2*)&u.y);
                s[0][0] -= a0.x; s[1][0] -= a0.y;
                s[0][1] -= a1.x; s[1][1] -= a1.y;
            }
        }

#pragma unroll
        for (int ch = 0; ch < 4; ++ch) {
            tot[ch] = ps[ch][1];
            wsc[ch] = wscan_dpp(tot[ch]);
        }
        if (lane == 63)
            WT[wid][0] = make_float4(wsc[0], wsc[1], wsc[2], wsc[3]);
        __syncthreads();   // b1

        float wo[4] = {0, 0, 0, 0};
        for (int w = 0; w < wid; ++w) {
            const float4 a = WT[w][0];
            wo[0] += a.x; wo[1] += a.y; wo[2] += a.z; wo[3] += a.w;
        }

        float pv1[4], pv2[4];
#pragma unroll
        for (int ch = 0; ch < 4; ++ch) {
            const float ex = wo[ch] + wsc[ch] - tot[ch];
            pv1[ch] = ex + ps[ch][0];
            pv2[ch] = ex + ps[ch][1];
        }
        {
            const int i1 = (x0 + 1) * 3, i2 = (x0 + 2) * 3;
            P2[i1 + 0] = make_float2(pv1[0], pv1[1]);
            P2[i1 + 1] = make_float2(pv1[2], pv1[3]);
            P2[i2 + 0] = make_float2(pv2[0], pv2[1]);
            P2[i2 + 1] = make_float2(pv2[2], pv2[3]);
        }
        __syncthreads();   // b2

#pragma unroll
        for (int r = 0; r < 2; ++r) {
            const int yr = y + r;
            const float icy = 1.0f / (float)(min(yr + RAD, H_ - 1) - max(yr - RAD, 0) + 1);
            const long long og = ib + (long long)yr * W_ + x0;
            const unsigned long long ru = nt_load_u64(Rimg + og);
            float rv[2];
            *(unsigned*)&rv[0] = (unsigned)(ru & 0xffffffffu);
            *(unsigned*)&rv[1] = (unsigned)(ru >> 32);
            float ov[2];
#pragma unroll
            for (int j = 0; j < 2; ++j) {
                const int x = x0 + j;
                const int hi = min(x + RAD + 1, W_) * 3;
                const int lo = max(x - RAD, 0) * 3;
                const float2 h2 = P2[hi + r];
                const float2 l2 = P2[lo + r];
                const float SA = h2.x - l2.x;
                const float SB = h2.y - l2.y;
                const float invN = icx[j] * icy;
                ov[j] = (SA * invN) * rv[j] + SB * invN;
            }
            unsigned long long uo =
                (unsigned long long)(*(const unsigned*)&ov[0]) |
                ((unsigned long long)(*(const unsigned*)&ov[1]) << 32);
            nt_store_u64(out + og, uo);   // out never re-read: NT stays
        }
        // no b3 (see gf_ab)
    }
}

// ---------------------------------------------------------------------------
extern "C" void kernel_launch(void* const* d_in, const int* in_sizes, int n_in,
                              void* d_out, int out_size, void* d_ws, size_t ws_size,
                              hipStream_t stream)
{
    const float* I = (const float*)d_in[0];   // image to filter
    const float* R = (const float*)d_in[1];   // guidance image
    float* out = (float*)d_out;

    const long long plane = (long long)H_ * W_;
    const int P_ = (int)(in_sizes[0] / plane);              // 24 planes
    const size_t ab_pb = (size_t)plane * sizeof(__half2);   // 4 MB/plane

    int CH = (int)(ws_size / ab_pb);
    if (CH > P_) CH = P_;
    if (CH < 1) CH = 1;

    __half2* AB = (__half2*)d_ws;

    for (int p0 = 0; p0 < P_; p0 += CH) {
        const int pc = (P_ - p0 < CH) ? (P_ - p0) : CH;
        const long long in_off = (long long)p0 * plane;
        const int nb = NSEG * pc;   // 32*pc

        hipLaunchKernelGGL(gf_ab, dim3(nb), dim3(NT), 0, stream,
                           I, R, in_off, nb, AB);
        hipLaunchKernelGGL(gf_cd, dim3(nb), dim3(NT), 0, stream,
                           AB, R, in_off, nb, out);
    }
}